// Round 3
// baseline (431.026 us; speedup 1.0000x reference)
//
#include <hip/hip_runtime.h>
#include <math.h>

#define B_ 64
#define Q_ 50
#define N_ 32
#define E_ 64
#define D_ 128
#define H_ 4
#define EDIM_ 8
#define G_ (B_*Q_)

// d_ws layout (bytes)
#define WLP_OFF 0          // 4h x 4q x 128n x 32kk bf16 = 131072 B
#define WRP_OFF 131072
#define W1P_OFF 262144     // 4q x 128n x 32kk bf16 = 32768 B
#define W2P_OFF 294912
#define EW_OFF  327680     // 2 x 512 f32 = 4096 B
#define XA_OFF  331776     // G x 4096 bf16 (A-fragment packed) = 26214400 B

typedef __attribute__((ext_vector_type(8))) short short8;
typedef __attribute__((ext_vector_type(4))) float f32x4;

// XOR swizzle for [32][128] f32 LDS tiles (flips word-index bits 2..4).
__device__ __forceinline__ int swz(int r, int d) { return (r << 7) + (d ^ ((r & 7) << 2)); }

__device__ __forceinline__ unsigned short f2b(float f) {
  unsigned u = __float_as_uint(f);
  u += 0x7fffu + ((u >> 16) & 1u);
  return (unsigned short)(u >> 16);
}

// ---------------- prep kernel A: pack weights + EW table ----------------
__global__ __launch_bounds__(256)
void pack_weights(const float* __restrict__ Wl, const float* __restrict__ Wr,
                  const float* __restrict__ W1, const float* __restrict__ W2,
                  const float* __restrict__ embT, const float* __restrict__ We,
                  unsigned char* __restrict__ ws)
{
  const int i = blockIdx.x * 256 + threadIdx.x;
  unsigned short* wlp = (unsigned short*)(ws + WLP_OFF);
  unsigned short* wrp = (unsigned short*)(ws + WRP_OFF);
  unsigned short* w1p = (unsigned short*)(ws + W1P_OFF);
  unsigned short* w2p = (unsigned short*)(ws + W2P_OFF);
  float* ew = (float*)(ws + EW_OFF);
  if (i < 65536) {
    // B-packed: idx = ((h*4+q)*128 + n)*32 + kk  <=  W[(q*32+kk)][h*128+n]
    const int kk = i & 31, n = (i >> 5) & 127, q = (i >> 12) & 3, h = i >> 14;
    wlp[i] = f2b(Wl[(q * 32 + kk) * (H_ * D_) + h * D_ + n]);
    wrp[i] = f2b(Wr[(q * 32 + kk) * (H_ * D_) + h * D_ + n]);
  } else if (i < 65536 + 16384) {
    const int j = i - 65536;
    const int kk = j & 31, n = (j >> 5) & 127, q = j >> 12;
    w1p[j] = f2b(W1[(q * 32 + kk) * D_ + n]);
    w2p[j] = f2b(W2[(q * 32 + kk) * D_ + n]);
  } else if (i < 65536 + 16384 + 1024) {
    const int j = i - 65536 - 16384;
    const int w = j >> 9, hd = j & 511;
    float a = 0.f;
#pragma unroll
    for (int k = 0; k < EDIM_; ++k) a = fmaf(embT[w * EDIM_ + k], We[k * (H_ * D_) + hd], a);
    ew[j] = a;
  }
}

// ---------------- prep kernel B: LN1 + pack to A-fragment bf16 ----------------
__global__ __launch_bounds__(256)
void ln_pack(const float* __restrict__ qe, const float* __restrict__ ln1g,
             const float* __restrict__ ln1b, unsigned char* __restrict__ ws)
{
  const int g = blockIdx.x, t = threadIdx.x;
  const int r = t >> 3, d0 = (t & 7) << 4;
  const float* src = qe + ((size_t)g * N_ + r) * D_ + d0;
  float v[16];
  float s = 0.f, ss = 0.f;
#pragma unroll
  for (int i = 0; i < 16; ++i) { float x = src[i]; v[i] = x; s += x; ss += x * x; }
#pragma unroll
  for (int m = 1; m < 8; m <<= 1) { s += __shfl_xor(s, m); ss += __shfl_xor(ss, m); }
  const float mu = s * (1.f / 128.f);
  const float inv = rsqrtf(ss * (1.f / 128.f) - mu * mu + 1e-5f);
  unsigned short o[16] __attribute__((aligned(16)));
#pragma unroll
  for (int i = 0; i < 16; ++i)
    o[i] = f2b((v[i] - mu) * inv * ln1g[d0 + i] + ln1b[d0 + i]);
  unsigned short* xa = (unsigned short*)(ws + XA_OFF) + (size_t)g * 4096;
  const int c = r >> 4;
#pragma unroll
  for (int p = 0; p < 2; ++p) {
    const int k8 = d0 + p * 8;
    const int q = k8 >> 5, lhi = (k8 >> 3) & 3;
    const int idx = ((c * 4 + q) * 64 + (lhi * 16 + (r & 15))) * 8;
    *(float4*)&xa[idx] = *(const float4*)&o[p * 8];
  }
}

// ---------------- MFMA GEMM: [32 x 128] = A[32x128] @ Bpacked[128x128] ----------------
// Each wave: n-quarter nq (32 cols), both m-tiles. Out: f32 swizzled LDS + bias + leaky.
__device__ __forceinline__ void gemm_e(const short8 aF[2][4], const unsigned short* __restrict__ Bp,
                                       const float* __restrict__ bias, float slope,
                                       float* __restrict__ dst, int lane, int nq)
{
#pragma unroll
  for (int nt = 0; nt < 2; ++nt) {
    const int col = nq * 32 + nt * 16 + (lane & 15);
    f32x4 acc0 = {0.f, 0.f, 0.f, 0.f}, acc1 = {0.f, 0.f, 0.f, 0.f};
#pragma unroll
    for (int q = 0; q < 4; ++q) {
      const short8 b = *(const short8*)&Bp[((q << 7) + col) * 32 + ((lane >> 4) << 3)];
      acc0 = __builtin_amdgcn_mfma_f32_16x16x32_bf16(aF[0][q], b, acc0, 0, 0, 0);
      acc1 = __builtin_amdgcn_mfma_f32_16x16x32_bf16(aF[1][q], b, acc1, 0, 0, 0);
    }
    const float bb = bias[col];
    const int r0 = (lane >> 4) << 2;
#pragma unroll
    for (int r = 0; r < 4; ++r) {
      float v0 = acc0[r] + bb; v0 = v0 >= 0.f ? v0 : slope * v0;
      float v1 = acc1[r] + bb; v1 = v1 >= 0.f ? v1 : slope * v1;
      dst[swz(r0 + r, col)] = v0;
      dst[swz(16 + r0 + r, col)] = v1;
    }
  }
}

// convert f32 swizzled LDS tile -> A fragment (bf16)
__device__ __forceinline__ short8 cvt_frag(const float* __restrict__ S, int c, int q, int lane)
{
  const int m = c * 16 + (lane & 15);
  const int k0 = q * 32 + ((lane >> 4) << 3);
  const float4 x0 = *(const float4*)&S[swz(m, k0)];
  const float4 x1 = *(const float4*)&S[swz(m, k0 + 4)];
  const float v[8] = {x0.x, x0.y, x0.z, x0.w, x1.x, x1.y, x1.z, x1.w};
  short8 r;
#pragma unroll
  for (int j = 0; j < 8; ++j) r[j] = (short)f2b(v[j]);
  return r;
}

// ---------------- main fused kernel: one block per group ----------------
__global__ __launch_bounds__(256, 3)
void gat_main(const unsigned char* __restrict__ ws,
              const int* __restrict__ qmask, const int* __restrict__ eidx,
              const int* __restrict__ ewt, const int* __restrict__ emsk,
              const float* __restrict__ bl, const float* __restrict__ br,
              const float* __restrict__ att, const float* __restrict__ gatb,
              const float* __restrict__ b1, const float* __restrict__ b2,
              const float* __restrict__ ln2g, const float* __restrict__ ln2b,
              float* __restrict__ out)
{
  const int g = blockIdx.x, t = threadIdx.x;
  const int lane = t & 63, wave = t >> 6;

  __shared__ float sXl[N_ * D_], sXr[N_ * D_], sAgg[N_ * D_];
  __shared__ float sEW[2][D_];
  __shared__ float sAtt[D_];
  __shared__ int sSrc[E_], sDst[E_], sWt[E_];
  __shared__ float sEm[E_], sExpE[E_], sLogit[E_];
  __shared__ float sLogitS[N_], sWs[N_], sNm[N_], sC0[N_], sC1[N_];
  __shared__ int sDeg[N_], sStart[N_], sCur[N_], sOrder[E_];
  __shared__ float sPool[D_];
  __shared__ float sValid, sNmSum;

  // A fragments for this lane (reused for all 8 E2 GEMMs)
  short8 aF[2][4];
  {
    const short8* xa = (const short8*)(ws + XA_OFF) + (size_t)g * 512;
#pragma unroll
    for (int c = 0; c < 2; ++c)
#pragma unroll
      for (int q = 0; q < 4; ++q)
        aF[c][q] = xa[(c * 4 + q) * 64 + lane];
  }

#pragma unroll
  for (int i = 0; i < 16; ++i) sAgg[(t << 4) + i] = 0.f;
  if (t < E_) {
    sSrc[t] = eidx[(size_t)g * 2 * E_ + t];
    sDst[t] = eidx[(size_t)g * 2 * E_ + E_ + t];
    sWt[t] = ewt[(size_t)g * E_ + t];
    sEm[t] = (float)emsk[(size_t)g * E_ + t];
  } else if (t >= 64 && t < 96) {
    sNm[t - 64] = (float)qmask[(size_t)g * N_ + (t - 64)];
  }
  __syncthreads();

  // per-node degree + edge-weight-class coefficients (loop_attr via EW linearity)
  if (t < N_) {
    float cnt = 0.f; int dg = 0; float c0 = 0.f, c1 = 0.f;
    for (int e = 0; e < E_; ++e) {
      if (sDst[e] == t) {
        ++dg;
        const float m = sEm[e];
        cnt += m;
        if (sWt[e] == 0) c0 += m; else c1 += m;
      }
    }
    sDeg[t] = dg;
    const float rinv = 1.f / fmaxf(cnt, 1.f);
    sC0[t] = c0 * rinv; sC1[t] = c1 * rinv;
  }
  __syncthreads();
  if (t == 0) {
    int acc = 0;
    for (int n = 0; n < N_; ++n) { sStart[n] = acc; sCur[n] = acc; acc += sDeg[n]; }
    for (int e = 0; e < E_; ++e) { int dn = sDst[e]; sOrder[sCur[dn]++] = e; }
  } else if (t == 64) {
    float nms = 0.f; for (int n = 0; n < N_; ++n) nms += sNm[n];
    float ems = 0.f; for (int e = 0; e < E_; ++e) ems += sEm[e];
    sNmSum = nms;
    sValid = (nms > 0.f && ems > 0.f) ? 1.f : 0.f;
  }
  __syncthreads();

  const unsigned short* wlp = (const unsigned short*)(ws + WLP_OFF);
  const unsigned short* wrp = (const unsigned short*)(ws + WRP_OFF);
  const float* ew = (const float*)(ws + EW_OFF);

  for (int h = 0; h < H_; ++h) {
    // stage per-head tables (no dependency on GEMM output)
    sEW[t >> 7][t & 127] = ew[(t >> 7) * (H_ * D_) + h * D_ + (t & 127)];
    if (t < 32) *(float4*)&sAtt[t << 2] = *(const float4*)&att[h * D_ + (t << 2)];
    // E2: xl / xr projections via MFMA
    gemm_e(aF, wlp + h * 16384, bl + h * D_, 1.0f, sXl, lane, wave);
    gemm_e(aF, wrp + h * 16384, br + h * D_, 1.0f, sXr, lane, wave);
    __syncthreads();
    // E3: edge logits (4 lanes/edge)
    {
      const int e = t >> 2, qu = t & 3;
      const int sn = sSrc[e], dn = sDst[e];
      const float* ewr = sEW[sWt[e]];
      float dot = 0.f;
#pragma unroll
      for (int i = 0; i < 32; ++i) {
        const int d = qu + (i << 2);
        float z = sXl[swz(sn, d)] + sXr[swz(dn, d)] + ewr[d];
        z = z >= 0.f ? z : 0.2f * z;
        dot = fmaf(z, sAtt[d], dot);
      }
      dot += __shfl_xor(dot, 1);
      dot += __shfl_xor(dot, 2);
      if (qu == 0) sLogit[e] = (sEm[e] > 0.f) ? dot : -1e30f;
    }
    // E4: self-loop logits (8 lanes/node)
    {
      const int n = t >> 3, l8 = t & 7;
      const float c0 = sC0[n], c1 = sC1[n];
      float dot = 0.f;
#pragma unroll
      for (int i = 0; i < 16; ++i) {
        const int d = l8 + (i << 3);
        float z = sXl[swz(n, d)] + sXr[swz(n, d)] + c0 * sEW[0][d] + c1 * sEW[1][d];
        z = z >= 0.f ? z : 0.2f * z;
        dot = fmaf(z, sAtt[d], dot);
      }
      dot += __shfl_xor(dot, 1);
      dot += __shfl_xor(dot, 2);
      dot += __shfl_xor(dot, 4);
      if (l8 == 0) sLogitS[n] = dot;
    }
    __syncthreads();
    // E5: deterministic per-node segment softmax
    if (t < N_) {
      const int st = sStart[t], de = sDeg[t];
      float m = sLogitS[t];
      for (int j = 0; j < de; ++j) m = fmaxf(m, sLogit[sOrder[st + j]]);
      const float es = __expf(sLogitS[t] - m);
      float den = es;
      for (int j = 0; j < de; ++j) {
        const int e = sOrder[st + j];
        const float ex = (sEm[e] > 0.f) ? __expf(sLogit[e] - m) : 0.f;
        sExpE[e] = ex;
        den += ex;
      }
      const float rden = 1.f / den;
      sWs[t] = es * rden;
      for (int j = 0; j < de; ++j) sExpE[sOrder[st + j]] *= rden;
    }
    __syncthreads();
    // E6: weighted aggregation, accumulate head mean
    {
      const int n = t >> 3, l8 = t & 7;
      const int st = sStart[n], de = sDeg[n];
      float acc[16] = {};
      for (int j = 0; j < de; ++j) {
        const int e = sOrder[st + j];
        const float w = sExpE[e];
        const int sn = sSrc[e];
#pragma unroll
        for (int i = 0; i < 16; ++i) acc[i] = fmaf(w, sXl[swz(sn, l8 + (i << 3))], acc[i]);
      }
      const float wsf = sWs[n];
#pragma unroll
      for (int i = 0; i < 16; ++i) {
        const int d = l8 + (i << 3);
        sAgg[swz(n, d)] += 0.25f * fmaf(wsf, sXl[swz(n, d)], acc[i]);
      }
    }
    __syncthreads();
  }

  // gout = agg + gat_b  (stage gatb via sAtt)
  if (t < 32) *(float4*)&sAtt[t << 2] = *(const float4*)&gatb[t << 2];
  __syncthreads();
  {
    const int n = t >> 3, l8 = t & 7;
#pragma unroll
    for (int i = 0; i < 16; ++i) {
      const int d = l8 + (i << 3);
      sAgg[swz(n, d)] += sAtt[d];
    }
  }
  __syncthreads();

  // FFN via MFMA
  {
    short8 aG[2][4];
#pragma unroll
    for (int c = 0; c < 2; ++c)
#pragma unroll
      for (int q = 0; q < 4; ++q) aG[c][q] = cvt_frag(sAgg, c, q, lane);
    gemm_e(aG, (const unsigned short*)(ws + W1P_OFF), b1, 0.01f, sXl, lane, wave);
    __syncthreads();
#pragma unroll
    for (int c = 0; c < 2; ++c)
#pragma unroll
      for (int q = 0; q < 4; ++q) aG[c][q] = cvt_frag(sXl, c, q, lane);
    gemm_e(aG, (const unsigned short*)(ws + W2P_OFF), b2, 1.0f, sXr, lane, wave);
  }
  __syncthreads();

  // masked mean pool
  if (t < D_) {
    float acc = 0.f;
    for (int n = 0; n < N_; ++n) acc = fmaf(sXr[swz(n, t)], sNm[n], acc);
    sPool[t] = acc * (1.f / fmaxf(sNmSum, 1.f)) * sValid;
  }
  __syncthreads();
  // LN2 + store
  if (t < 64) {
    const float v0 = sPool[t], v1 = sPool[t + 64];
    float s = v0 + v1, ss = v0 * v0 + v1 * v1;
#pragma unroll
    for (int m = 1; m < 64; m <<= 1) { s += __shfl_xor(s, m); ss += __shfl_xor(ss, m); }
    const float mu = s * (1.f / 128.f);
    const float inv = rsqrtf(ss * (1.f / 128.f) - mu * mu + 1e-5f);
    float* op = out + (size_t)g * D_;
    op[t] = (v0 - mu) * inv * ln2g[t] + ln2b[t];
    op[t + 64] = (v1 - mu) * inv * ln2g[t + 64] + ln2b[t + 64];
  }
}

extern "C" void kernel_launch(void* const* d_in, const int* in_sizes, int n_in,
                              void* d_out, int out_size, void* d_ws, size_t ws_size,
                              hipStream_t stream) {
  (void)in_sizes; (void)n_in; (void)out_size; (void)ws_size;
  const float* qe   = (const float*)d_in[0];
  const int*   qm   = (const int*)d_in[1];
  const int*   ei   = (const int*)d_in[2];
  const int*   ew   = (const int*)d_in[3];
  const int*   em   = (const int*)d_in[4];
  const float* ln1g = (const float*)d_in[5];
  const float* ln1b = (const float*)d_in[6];
  const float* embT = (const float*)d_in[7];
  const float* Wl   = (const float*)d_in[8];
  const float* bl   = (const float*)d_in[9];
  const float* Wr   = (const float*)d_in[10];
  const float* br   = (const float*)d_in[11];
  const float* We   = (const float*)d_in[12];
  const float* att  = (const float*)d_in[13];
  const float* gatb = (const float*)d_in[14];
  const float* W1   = (const float*)d_in[15];
  const float* b1   = (const float*)d_in[16];
  const float* W2   = (const float*)d_in[17];
  const float* b2   = (const float*)d_in[18];
  const float* ln2g = (const float*)d_in[19];
  const float* ln2b = (const float*)d_in[20];
  float* out = (float*)d_out;
  unsigned char* ws = (unsigned char*)d_ws;

  pack_weights<<<dim3(324), dim3(256), 0, stream>>>(Wl, Wr, W1, W2, embT, We, ws);
  ln_pack<<<dim3(G_), dim3(256), 0, stream>>>(qe, ln1g, ln1b, ws);
  gat_main<<<dim3(G_), dim3(256), 0, stream>>>(ws, qm, ei, ew, em, bl, br, att, gatb,
                                               b1, b2, ln2g, ln2b, out);
}

// Round 4
// 311.786 us; speedup vs baseline: 1.3824x; 1.3824x over previous
//
#include <hip/hip_runtime.h>
#include <math.h>

#define B_ 64
#define Q_ 50
#define N_ 32
#define E_ 64
#define D_ 128
#define H_ 4
#define EDIM_ 8
#define G_ (B_*Q_)

// d_ws layout (bytes)
#define WLP_OFF 0          // 4h x 4q x 128n x 32kk bf16 = 131072 B
#define WRP_OFF 131072
#define W1P_OFF 262144     // 4q x 128n x 32kk bf16 = 32768 B
#define W2P_OFF 294912
#define EW_OFF  327680     // 2 x 512 f32 = 4096 B  (emb_table @ We)

typedef __attribute__((ext_vector_type(8))) short short8;
typedef __attribute__((ext_vector_type(4))) float f32x4;
typedef unsigned short ushort_t;
typedef unsigned long long u64;

// bf16 [32][128] LDS tile, XOR-swizzled at 16B granularity (8 elems).
// elem offset; for 16B vector access pass d ≡ 0 (mod 8).
__device__ __forceinline__ int boff(int r, int d) {
  return (r << 7) + ((d & 0x78) ^ ((r & 7) << 3)) + (d & 7);
}

__device__ __forceinline__ ushort_t f2b(float f) {
  unsigned u = __float_as_uint(f);
  u += 0x7fffu + ((u >> 16) & 1u);
  return (ushort_t)(u >> 16);
}
__device__ __forceinline__ float b2f(ushort_t u) {
  return __uint_as_float(((unsigned)u) << 16);
}

// ---------------- prep kernel: pack weights bf16 + EW = emb_table @ We ----------------
__global__ __launch_bounds__(256)
void pack_weights(const float* __restrict__ Wl, const float* __restrict__ Wr,
                  const float* __restrict__ W1, const float* __restrict__ W2,
                  const float* __restrict__ embT, const float* __restrict__ We,
                  unsigned char* __restrict__ ws)
{
  const int i = blockIdx.x * 256 + threadIdx.x;
  ushort_t* wlp = (ushort_t*)(ws + WLP_OFF);
  ushort_t* wrp = (ushort_t*)(ws + WRP_OFF);
  ushort_t* w1p = (ushort_t*)(ws + W1P_OFF);
  ushort_t* w2p = (ushort_t*)(ws + W2P_OFF);
  float* ew = (float*)(ws + EW_OFF);
  if (i < 65536) {
    // B-packed: idx = ((h*4+q)*128 + n)*32 + kk  <=  W[(q*32+kk)][h*128+n]
    const int kk = i & 31, n = (i >> 5) & 127, q = (i >> 12) & 3, h = i >> 14;
    wlp[i] = f2b(Wl[(q * 32 + kk) * (H_ * D_) + h * D_ + n]);
    wrp[i] = f2b(Wr[(q * 32 + kk) * (H_ * D_) + h * D_ + n]);
  } else if (i < 65536 + 16384) {
    const int j = i - 65536;
    const int kk = j & 31, n = (j >> 5) & 127, q = j >> 12;
    w1p[j] = f2b(W1[(q * 32 + kk) * D_ + n]);
    w2p[j] = f2b(W2[(q * 32 + kk) * D_ + n]);
  } else if (i < 65536 + 16384 + 1024) {
    const int j = i - 65536 - 16384;
    const int w = j >> 9, hd = j & 511;   // ew layout: [w][h*128+d]
    float a = 0.f;
#pragma unroll
    for (int k = 0; k < EDIM_; ++k) a = fmaf(embT[w * EDIM_ + k], We[k * (H_ * D_) + hd], a);
    ew[j] = a;
  }
}

// ---------------- MFMA GEMM: [32 x 128] = A[32x128] @ Bpacked[128x128], bf16 out ----------------
__device__ __forceinline__ void gemm_e(const short8 aF[2][4], const ushort_t* __restrict__ Bp,
                                       const float* __restrict__ bias, float slope,
                                       ushort_t* __restrict__ dst, int lane, int nq)
{
#pragma unroll
  for (int nt = 0; nt < 2; ++nt) {
    const int col = nq * 32 + nt * 16 + (lane & 15);
    f32x4 acc0 = {0.f, 0.f, 0.f, 0.f}, acc1 = {0.f, 0.f, 0.f, 0.f};
#pragma unroll
    for (int q = 0; q < 4; ++q) {
      const short8 b = *(const short8*)&Bp[((q << 7) + col) * 32 + ((lane >> 4) << 3)];
      acc0 = __builtin_amdgcn_mfma_f32_16x16x32_bf16(aF[0][q], b, acc0, 0, 0, 0);
      acc1 = __builtin_amdgcn_mfma_f32_16x16x32_bf16(aF[1][q], b, acc1, 0, 0, 0);
    }
    const float bb = bias[col];
    const int r0 = (lane >> 4) << 2;
#pragma unroll
    for (int r = 0; r < 4; ++r) {
      float v0 = acc0[r] + bb; v0 = v0 >= 0.f ? v0 : slope * v0;
      float v1 = acc1[r] + bb; v1 = v1 >= 0.f ? v1 : slope * v1;
      dst[boff(r0 + r, col)] = f2b(v0);
      dst[boff(16 + r0 + r, col)] = f2b(v1);
    }
  }
}

// ---------------- main fused kernel: one block per group ----------------
__global__ __launch_bounds__(256, 4)
void gat_main(const unsigned char* __restrict__ ws,
              const float* __restrict__ qe,
              const float* __restrict__ ln1g, const float* __restrict__ ln1b,
              const int* __restrict__ qmask, const int* __restrict__ eidx,
              const int* __restrict__ ewt, const int* __restrict__ emsk,
              const float* __restrict__ bl, const float* __restrict__ br,
              const float* __restrict__ att, const float* __restrict__ gatb,
              const float* __restrict__ b1, const float* __restrict__ b2,
              const float* __restrict__ ln2g, const float* __restrict__ ln2b,
              float* __restrict__ out)
{
  const int g = blockIdx.x, t = threadIdx.x;
  const int lane = t & 63, wave = t >> 6;

  __shared__ ushort_t sX[N_ * D_];    // LN1 bf16 A-matrix; later FFN scratch
  __shared__ ushort_t sXl[N_ * D_];   // xl (per head); later FFN h1
  __shared__ ushort_t sXr[N_ * D_];   // xr (per head); later FFN h2
  __shared__ ushort_t sEW[2 * H_ * D_];  // [w][h][d] bf16
  __shared__ ushort_t sAtt[H_ * D_];     // [h][d] bf16
  __shared__ u64 sInc[N_];            // per-node valid incoming-edge bitmask
  __shared__ int sSrc[E_], sDst[E_], sWt[E_];
  __shared__ float sEm[E_], sLogit[E_];
  __shared__ float sLogitS[N_], sNm[N_], sC0[N_], sC1[N_];
  __shared__ float sPool[D_];
  __shared__ float sValid, sNmSum;

  // ---- Phase A: LN1 -> bf16 swizzled LDS; stage edges/masks/tables ----
  {
    const int r = t >> 3, d0 = (t & 7) << 4;
    const float* src = qe + ((size_t)g * N_ + r) * D_ + d0;
    float v[16];
    float s = 0.f, ss = 0.f;
#pragma unroll
    for (int i = 0; i < 16; ++i) { float x = src[i]; v[i] = x; s += x; ss += x * x; }
#pragma unroll
    for (int m = 1; m < 8; m <<= 1) { s += __shfl_xor(s, m); ss += __shfl_xor(ss, m); }
    const float mu = s * (1.f / 128.f);
    const float inv = rsqrtf(ss * (1.f / 128.f) - mu * mu + 1e-5f);
#pragma unroll
    for (int i = 0; i < 16; ++i)
      sX[boff(r, d0 + i)] = f2b((v[i] - mu) * inv * ln1g[d0 + i] + ln1b[d0 + i]);
  }
  {
    const float* ewg = (const float*)(ws + EW_OFF);
    const int j = t << 2;                      // 1024 EW entries, 4 per thread
    float4 e4 = *(const float4*)&ewg[j];
    sEW[j] = f2b(e4.x); sEW[j + 1] = f2b(e4.y); sEW[j + 2] = f2b(e4.z); sEW[j + 3] = f2b(e4.w);
    if (t < 128) {
      float4 a4 = *(const float4*)&att[j];
      sAtt[j] = f2b(a4.x); sAtt[j + 1] = f2b(a4.y); sAtt[j + 2] = f2b(a4.z); sAtt[j + 3] = f2b(a4.w);
    }
  }
  if (t < E_) {
    sSrc[t] = eidx[(size_t)g * 2 * E_ + t];
    sDst[t] = eidx[(size_t)g * 2 * E_ + E_ + t];
    sWt[t] = ewt[(size_t)g * E_ + t];
    sEm[t] = (float)emsk[(size_t)g * E_ + t];
  } else if (t < 96) {
    sNm[t - 64] = (float)qmask[(size_t)g * N_ + (t - 64)];
  }
  __syncthreads();

  // ---- A fragments (reused for all 8 E2 GEMMs) ----
  short8 aF[2][4];
#pragma unroll
  for (int c = 0; c < 2; ++c)
#pragma unroll
    for (int q = 0; q < 4; ++q)
      aF[c][q] = *(const short8*)&sX[boff(c * 16 + (lane & 15), q * 32 + ((lane >> 4) << 3))];

  // ---- ballot-based per-node masks (wave w owns nodes 8w..8w+7) ----
  {
    const int dl = sDst[lane];
    const float eml = sEm[lane];
    const int wtl = sWt[lane];
    const bool val = eml > 0.f;
    const u64 wt0m = __ballot(wtl == 0);
#pragma unroll
    for (int k = 0; k < 8; ++k) {
      const int n = wave * 8 + k;
      const u64 inc = __ballot(val && dl == n);
      if (lane == k) {
        sInc[n] = inc;
        const float cnt = (float)__popcll(inc);
        const float c0 = (float)__popcll(inc & wt0m);
        const float rinv = 1.f / fmaxf(cnt, 1.f);
        sC0[n] = c0 * rinv;
        sC1[n] = (cnt - c0) * rinv;
      }
    }
    if (wave == 3) {
      float nmv = (lane < 32) ? sNm[lane] : 0.f;
      float emv = eml;
#pragma unroll
      for (int m = 1; m < 64; m <<= 1) { nmv += __shfl_xor(nmv, m); emv += __shfl_xor(emv, m); }
      if (lane == 0) {
        sNmSum = nmv;
        sValid = (nmv > 0.f && emv > 0.f) ? 1.f : 0.f;
      }
    }
  }

  const ushort_t* wlp = (const ushort_t*)(ws + WLP_OFF);
  const ushort_t* wrp = (const ushort_t*)(ws + WRP_OFF);

  float accH[16] = {};   // per-thread head-mean accumulator: node t>>3, d = (t&7)+8i

  for (int h = 0; h < H_; ++h) {
    // E2: xl / xr projections via MFMA
    gemm_e(aF, wlp + h * 16384, bl + h * D_, 1.0f, sXl, lane, wave);
    gemm_e(aF, wrp + h * 16384, br + h * D_, 1.0f, sXr, lane, wave);
    __syncthreads();
    // E3: edge logits (4 lanes/edge)
    {
      const int e = t >> 2, qu = t & 3;
      const int sn = sSrc[e], dn = sDst[e];
      const ushort_t* ewr = &sEW[(sWt[e] << 9) + (h << 7)];
      const ushort_t* atr = &sAtt[h << 7];
      float dot = 0.f;
#pragma unroll
      for (int i = 0; i < 32; ++i) {
        const int d = qu + (i << 2);
        float z = b2f(sXl[boff(sn, d)]) + b2f(sXr[boff(dn, d)]) + b2f(ewr[d]);
        z = z >= 0.f ? z : 0.2f * z;
        dot = fmaf(z, b2f(atr[d]), dot);
      }
      dot += __shfl_xor(dot, 1);
      dot += __shfl_xor(dot, 2);
      if (qu == 0) sLogit[e] = (sEm[e] > 0.f) ? dot : -1e30f;
    }
    // E4: self-loop logits (8 lanes/node)
    {
      const int n = t >> 3, l8 = t & 7;
      const float c0 = sC0[n], c1 = sC1[n];
      const ushort_t* atr = &sAtt[h << 7];
      float dot = 0.f;
#pragma unroll
      for (int i = 0; i < 16; ++i) {
        const int d = l8 + (i << 3);
        float z = b2f(sXl[boff(n, d)]) + b2f(sXr[boff(n, d)])
                + c0 * b2f(sEW[(h << 7) + d]) + c1 * b2f(sEW[512 + (h << 7) + d]);
        z = z >= 0.f ? z : 0.2f * z;
        dot = fmaf(z, b2f(atr[d]), dot);
      }
      dot += __shfl_xor(dot, 1);
      dot += __shfl_xor(dot, 2);
      dot += __shfl_xor(dot, 4);
      if (l8 == 0) sLogitS[n] = dot;
    }
    __syncthreads();
    // E6: softmax (redundant per 8-lane node group, in registers) + aggregation
    {
      const int n = t >> 3, l8 = t & 7;
      const u64 mb = sInc[n];
      float mx = sLogitS[n];
      u64 m2 = mb;
      while (m2) { const int e = __builtin_ctzll(m2); m2 &= m2 - 1; mx = fmaxf(mx, sLogit[e]); }
      const float es = __expf(sLogitS[n] - mx);
      float den = es;
      float S[16] = {};
      m2 = mb;
      while (m2) {
        const int e = __builtin_ctzll(m2); m2 &= m2 - 1;
        const float w = __expf(sLogit[e] - mx);
        den += w;
        const int sn = sSrc[e];
#pragma unroll
        for (int i = 0; i < 16; ++i) S[i] = fmaf(w, b2f(sXl[boff(sn, l8 + (i << 3))]), S[i]);
      }
      const float rd = 0.25f / den;
#pragma unroll
      for (int i = 0; i < 16; ++i)
        accH[i] = fmaf(rd, S[i] + es * b2f(sXl[boff(n, l8 + (i << 3))]), accH[i]);
    }
    __syncthreads();
  }

  // ---- gout = head-mean + gat_b -> bf16 A-matrix in sX ----
  {
    const int n = t >> 3, l8 = t & 7;
#pragma unroll
    for (int i = 0; i < 16; ++i) {
      const int d = l8 + (i << 3);
      sX[boff(n, d)] = f2b(accH[i] + gatb[d]);
    }
  }
  __syncthreads();

  // ---- FFN via MFMA ----
  {
    short8 aG[2][4];
#pragma unroll
    for (int c = 0; c < 2; ++c)
#pragma unroll
      for (int q = 0; q < 4; ++q)
        aG[c][q] = *(const short8*)&sX[boff(c * 16 + (lane & 15), q * 32 + ((lane >> 4) << 3))];
    gemm_e(aG, (const ushort_t*)(ws + W1P_OFF), b1, 0.01f, sXl, lane, wave);
    __syncthreads();
#pragma unroll
    for (int c = 0; c < 2; ++c)
#pragma unroll
      for (int q = 0; q < 4; ++q)
        aG[c][q] = *(const short8*)&sXl[boff(c * 16 + (lane & 15), q * 32 + ((lane >> 4) << 3))];
    gemm_e(aG, (const ushort_t*)(ws + W2P_OFF), b2, 1.0f, sXr, lane, wave);
  }
  __syncthreads();

  // ---- masked mean pool ----
  if (t < D_) {
    float acc = 0.f;
    for (int n = 0; n < N_; ++n) acc = fmaf(b2f(sXr[boff(n, t)]), sNm[n], acc);
    sPool[t] = acc * (1.f / fmaxf(sNmSum, 1.f)) * sValid;
  }
  __syncthreads();
  // ---- LN2 + store ----
  if (t < 64) {
    const float v0 = sPool[t], v1 = sPool[t + 64];
    float s = v0 + v1, ss = v0 * v0 + v1 * v1;
#pragma unroll
    for (int m = 1; m < 64; m <<= 1) { s += __shfl_xor(s, m); ss += __shfl_xor(ss, m); }
    const float mu = s * (1.f / 128.f);
    const float inv = rsqrtf(ss * (1.f / 128.f) - mu * mu + 1e-5f);
    float* op = out + (size_t)g * D_;
    op[t] = (v0 - mu) * inv * ln2g[t] + ln2b[t];
    op[t + 64] = (v1 - mu) * inv * ln2g[t + 64] + ln2b[t + 64];
  }
}

extern "C" void kernel_launch(void* const* d_in, const int* in_sizes, int n_in,
                              void* d_out, int out_size, void* d_ws, size_t ws_size,
                              hipStream_t stream) {
  (void)in_sizes; (void)n_in; (void)out_size; (void)ws_size;
  const float* qe   = (const float*)d_in[0];
  const int*   qm   = (const int*)d_in[1];
  const int*   ei   = (const int*)d_in[2];
  const int*   ew   = (const int*)d_in[3];
  const int*   em   = (const int*)d_in[4];
  const float* ln1g = (const float*)d_in[5];
  const float* ln1b = (const float*)d_in[6];
  const float* embT = (const float*)d_in[7];
  const float* Wl   = (const float*)d_in[8];
  const float* bl   = (const float*)d_in[9];
  const float* Wr   = (const float*)d_in[10];
  const float* br   = (const float*)d_in[11];
  const float* We   = (const float*)d_in[12];
  const float* att  = (const float*)d_in[13];
  const float* gatb = (const float*)d_in[14];
  const float* W1   = (const float*)d_in[15];
  const float* b1   = (const float*)d_in[16];
  const float* W2   = (const float*)d_in[17];
  const float* b2   = (const float*)d_in[18];
  const float* ln2g = (const float*)d_in[19];
  const float* ln2b = (const float*)d_in[20];
  float* out = (float*)d_out;
  unsigned char* ws = (unsigned char*)d_ws;

  pack_weights<<<dim3(324), dim3(256), 0, stream>>>(Wl, Wr, W1, W2, embT, We, ws);
  gat_main<<<dim3(G_), dim3(256), 0, stream>>>(ws, qe, ln1g, ln1b, qm, ei, ew, em,
                                               bl, br, att, gatb, b1, b2, ln2g, ln2b, out);
}

// Round 6
// 192.344 us; speedup vs baseline: 2.2409x; 1.6210x over previous
//
#include <hip/hip_runtime.h>
#include <math.h>

#define B_ 64
#define Q_ 50
#define N_ 32
#define E_ 64
#define D_ 128
#define H_ 4
#define EDIM_ 8
#define G_ (B_*Q_)

// d_ws layout (bytes)
#define WLP_OFF 0          // 4h x 4q x 128n x 32kk bf16 = 131072 B
#define WRP_OFF 131072
#define W1P_OFF 262144     // 4q x 128n x 32kk bf16 = 32768 B
#define W2P_OFF 294912
#define EW_OFF  327680     // 2 x 512 f32 = 4096 B  (emb_table @ We)

typedef __attribute__((ext_vector_type(8))) short short8;
typedef __attribute__((ext_vector_type(4))) float f32x4;
typedef unsigned short ushort_t;
typedef unsigned long long u64;

// bf16 [32][128] LDS tile, XOR-swizzled at 16B granularity (8 elems).
__device__ __forceinline__ int boff(int r, int d) {
  return (r << 7) + ((d & 0x78) ^ ((r & 7) << 3)) + (d & 7);
}

__device__ __forceinline__ ushort_t f2b(float f) {
  unsigned u = __float_as_uint(f);
  u += 0x7fffu + ((u >> 16) & 1u);
  return (ushort_t)(u >> 16);
}
__device__ __forceinline__ float b2f(ushort_t u) {
  return __uint_as_float(((unsigned)u) << 16);
}
__device__ __forceinline__ float leaky(float v, float s) {
  return fmaxf(v, 0.f) + s * fminf(v, 0.f);
}

// ---------------- prep kernel: pack weights bf16 + EW = emb_table @ We ----------------
__global__ __launch_bounds__(256)
void pack_weights(const float* __restrict__ Wl, const float* __restrict__ Wr,
                  const float* __restrict__ W1, const float* __restrict__ W2,
                  const float* __restrict__ embT, const float* __restrict__ We,
                  unsigned char* __restrict__ ws)
{
  const int i = blockIdx.x * 256 + threadIdx.x;
  ushort_t* wlp = (ushort_t*)(ws + WLP_OFF);
  ushort_t* wrp = (ushort_t*)(ws + WRP_OFF);
  ushort_t* w1p = (ushort_t*)(ws + W1P_OFF);
  ushort_t* w2p = (ushort_t*)(ws + W2P_OFF);
  float* ew = (float*)(ws + EW_OFF);
  if (i < 65536) {
    // packed: idx = ((h*4+q)*128 + n)*32 + kk  <=  W[(q*32+kk)][h*128+n]
    const int kk = i & 31, n = (i >> 5) & 127, q = (i >> 12) & 3, h = i >> 14;
    wlp[i] = f2b(Wl[(q * 32 + kk) * (H_ * D_) + h * D_ + n]);
    wrp[i] = f2b(Wr[(q * 32 + kk) * (H_ * D_) + h * D_ + n]);
  } else if (i < 65536 + 16384) {
    const int j = i - 65536;
    const int kk = j & 31, n = (j >> 5) & 127, q = j >> 12;
    w1p[j] = f2b(W1[(q * 32 + kk) * D_ + n]);
    w2p[j] = f2b(W2[(q * 32 + kk) * D_ + n]);
  } else if (i < 65536 + 16384 + 1024) {
    const int j = i - 65536 - 16384;
    const int w = j >> 9, hd = j & 511;   // ew layout: [w][h*128+d]
    float a = 0.f;
#pragma unroll
    for (int k = 0; k < EDIM_; ++k) a = fmaf(embT[w * EDIM_ + k], We[k * (H_ * D_) + hd], a);
    ew[j] = a;
  }
}

// ---------------- MFMA GEMM (swapped operands): [32 x 128] = A[32x128] @ W[128x128] ----
// mfma(Wfrag, Xfrag) => D = (X W)^T tile: lane&15 = node, (lane>>4)*4+r = out-col.
// Epilogue: bias + leaky, pack 4 bf16 -> one 8B LDS write per tile.
__device__ __forceinline__ void gemm_e(const short8 aF[2][4], const ushort_t* __restrict__ Bp,
                                       const float* __restrict__ bias, float slope,
                                       ushort_t* __restrict__ dst, int lane, int nq)
{
#pragma unroll
  for (int nt = 0; nt < 2; ++nt) {
    const int colw = nq * 32 + nt * 16 + (lane & 15);
    const int oc0 = nq * 32 + nt * 16 + ((lane >> 4) << 2);
    const float4 bb = *(const float4*)&bias[oc0];
    f32x4 acc0 = {0.f, 0.f, 0.f, 0.f}, acc1 = {0.f, 0.f, 0.f, 0.f};
#pragma unroll
    for (int q = 0; q < 4; ++q) {
      const short8 b = *(const short8*)&Bp[((q << 7) + colw) * 32 + ((lane >> 4) << 3)];
      acc0 = __builtin_amdgcn_mfma_f32_16x16x32_bf16(b, aF[0][q], acc0, 0, 0, 0);
      acc1 = __builtin_amdgcn_mfma_f32_16x16x32_bf16(b, aF[1][q], acc1, 0, 0, 0);
    }
#pragma unroll
    for (int cc = 0; cc < 2; ++cc) {
      const f32x4 a = cc ? acc1 : acc0;
      const int node = cc * 16 + (lane & 15);
      float v;
      unsigned u0, u1;
      v = leaky(a[0] + bb.x, slope); u0 = f2b(v);
      v = leaky(a[1] + bb.y, slope); u0 |= ((unsigned)f2b(v)) << 16;
      v = leaky(a[2] + bb.z, slope); u1 = f2b(v);
      v = leaky(a[3] + bb.w, slope); u1 |= ((unsigned)f2b(v)) << 16;
      uint2 o; o.x = u0; o.y = u1;
      *(uint2*)&dst[boff(node, oc0)] = o;
    }
  }
}

// ---------------- main fused kernel: one block per group ----------------
__global__ __launch_bounds__(256, 5)
void gat_main(const unsigned char* __restrict__ ws,
              const float* __restrict__ qe,
              const float* __restrict__ ln1g, const float* __restrict__ ln1b,
              const int* __restrict__ qmask, const int* __restrict__ eidx,
              const int* __restrict__ ewt, const int* __restrict__ emsk,
              const float* __restrict__ bl, const float* __restrict__ br,
              const float* __restrict__ att, const float* __restrict__ gatb,
              const float* __restrict__ b1, const float* __restrict__ b2,
              const float* __restrict__ ln2g, const float* __restrict__ ln2b,
              float* __restrict__ out)
{
  const int g = blockIdx.x, t = threadIdx.x;
  const int lane = t & 63, wave = t >> 6;

  __shared__ __align__(16) ushort_t sX[N_ * D_];    // LN1 bf16 A-matrix; later gout
  __shared__ __align__(16) ushort_t sXl[N_ * D_];   // xl (per head); later FFN h1
  __shared__ __align__(16) ushort_t sXr[N_ * D_];   // xr (per head); later FFN h2
  __shared__ __align__(16) ushort_t sEW[2 * H_ * D_];  // [w][h][d] bf16
  __shared__ __align__(16) ushort_t sAtt[H_ * D_];     // [h][d] bf16
  __shared__ u64 sInc[N_];            // per-node valid incoming-edge bitmask
  __shared__ int sSrc[E_], sDst[E_], sWt[E_];
  __shared__ float sEm[E_], sLogit[E_];
  __shared__ float sLogitS[N_], sNm[N_], sC0[N_], sC1[N_];
  __shared__ float sPool[D_];
  __shared__ float sValid, sNmSum;

  // ---- Phase A: LN1 -> bf16 swizzled LDS (nontemporal qe); stage tables ----
  {
    const int r = t >> 3, d0 = (t & 7) << 4;
    const f32x4* src4 = (const f32x4*)(qe + ((size_t)g * N_ + r) * D_ + d0);
    f32x4 v4[4];
#pragma unroll
    for (int p = 0; p < 4; ++p) v4[p] = __builtin_nontemporal_load(src4 + p);
    const float* v = (const float*)v4;
    float s = 0.f, ss = 0.f;
#pragma unroll
    for (int i = 0; i < 16; ++i) { float x = v[i]; s += x; ss += x * x; }
#pragma unroll
    for (int m = 1; m < 8; m <<= 1) { s += __shfl_xor(s, m); ss += __shfl_xor(ss, m); }
    const float mu = s * (1.f / 128.f);
    const float inv = rsqrtf(ss * (1.f / 128.f) - mu * mu + 1e-5f);
#pragma unroll
    for (int i = 0; i < 16; ++i)
      sX[boff(r, d0 + i)] = f2b((v[i] - mu) * inv * ln1g[d0 + i] + ln1b[d0 + i]);
  }
  {
    const float* ewg = (const float*)(ws + EW_OFF);
    const int j = t << 2;                      // 1024 EW entries, 4 per thread
    float4 e4 = *(const float4*)&ewg[j];
    sEW[j] = f2b(e4.x); sEW[j + 1] = f2b(e4.y); sEW[j + 2] = f2b(e4.z); sEW[j + 3] = f2b(e4.w);
    if (t < 128) {
      float4 a4 = *(const float4*)&att[j];
      sAtt[j] = f2b(a4.x); sAtt[j + 1] = f2b(a4.y); sAtt[j + 2] = f2b(a4.z); sAtt[j + 3] = f2b(a4.w);
    }
  }
  if (t < E_) {
    sSrc[t] = eidx[(size_t)g * 2 * E_ + t];
    sDst[t] = eidx[(size_t)g * 2 * E_ + E_ + t];
    sWt[t] = ewt[(size_t)g * E_ + t];
    sEm[t] = (float)emsk[(size_t)g * E_ + t];
  } else if (t < 96) {
    sNm[t - 64] = (float)qmask[(size_t)g * N_ + (t - 64)];
  }
  __syncthreads();

  // ---- A fragments (double as MFMA B-operand; reused for all 8 E2 GEMMs) ----
  short8 aF[2][4];
#pragma unroll
  for (int c = 0; c < 2; ++c)
#pragma unroll
    for (int q = 0; q < 4; ++q)
      aF[c][q] = *(const short8*)&sX[boff(c * 16 + (lane & 15), q * 32 + ((lane >> 4) << 3))];

  // ---- ballot-based per-node masks (wave w owns nodes 8w..8w+7) ----
  {
    const int dl = sDst[lane];
    const float eml = sEm[lane];
    const int wtl = sWt[lane];
    const bool val = eml > 0.f;
    const u64 wt0m = __ballot(wtl == 0);
#pragma unroll
    for (int k = 0; k < 8; ++k) {
      const int n = wave * 8 + k;
      const u64 inc = __ballot(val && dl == n);
      if (lane == k) {
        sInc[n] = inc;
        const float cnt = (float)__popcll(inc);
        const float c0 = (float)__popcll(inc & wt0m);
        const float rinv = 1.f / fmaxf(cnt, 1.f);
        sC0[n] = c0 * rinv;
        sC1[n] = (cnt - c0) * rinv;
      }
    }
    if (wave == 3) {
      float nmv = (lane < 32) ? sNm[lane] : 0.f;
      float emv = eml;
#pragma unroll
      for (int m = 1; m < 64; m <<= 1) { nmv += __shfl_xor(nmv, m); emv += __shfl_xor(emv, m); }
      if (lane == 0) {
        sNmSum = nmv;
        sValid = (nmv > 0.f && emv > 0.f) ? 1.f : 0.f;
      }
    }
  }

  const ushort_t* wlp = (const ushort_t*)(ws + WLP_OFF);
  const ushort_t* wrp = (const ushort_t*)(ws + WRP_OFF);

  float accH[16] = {};   // node t>>3, d = (t&7)*16 + i

  for (int h = 0; h < H_; ++h) {
    // E2: xl / xr projections via MFMA
    gemm_e(aF, wlp + h * 16384, bl + h * D_, 1.0f, sXl, lane, wave);
    gemm_e(aF, wrp + h * 16384, br + h * D_, 1.0f, sXr, lane, wave);
    __syncthreads();
    // E3: edge logits (4 lanes/edge, vector LDS reads)
    {
      const int e = t >> 2, qu = t & 3;
      const int sn = sSrc[e], dn = sDst[e];
      const int ewb = (sWt[e] << 9) + (h << 7);
      float dot = 0.f;
#pragma unroll
      for (int ch = 0; ch < 4; ++ch) {
        const int dd = qu * 32 + ch * 8;
        const short8 xl8 = *(const short8*)&sXl[boff(sn, dd)];
        const short8 xr8 = *(const short8*)&sXr[boff(dn, dd)];
        const short8 ew8 = *(const short8*)&sEW[ewb + dd];
        const short8 at8 = *(const short8*)&sAtt[(h << 7) + dd];
#pragma unroll
        for (int j = 0; j < 8; ++j) {
          float z = b2f((ushort_t)xl8[j]) + b2f((ushort_t)xr8[j]) + b2f((ushort_t)ew8[j]);
          dot = fmaf(leaky(z, 0.2f), b2f((ushort_t)at8[j]), dot);
        }
      }
      dot += __shfl_xor(dot, 1);
      dot += __shfl_xor(dot, 2);
      if (qu == 0) sLogit[e] = (sEm[e] > 0.f) ? dot : -1e30f;
    }
    // E4: self-loop logits (8 lanes/node, vector LDS reads)
    {
      const int n = t >> 3, l8 = t & 7;
      const float c0 = sC0[n], c1 = sC1[n];
      float dot = 0.f;
#pragma unroll
      for (int ch = 0; ch < 2; ++ch) {
        const int dd = (l8 << 4) + ch * 8;
        const short8 xl8 = *(const short8*)&sXl[boff(n, dd)];
        const short8 xr8 = *(const short8*)&sXr[boff(n, dd)];
        const short8 e08 = *(const short8*)&sEW[(h << 7) + dd];
        const short8 e18 = *(const short8*)&sEW[512 + (h << 7) + dd];
        const short8 at8 = *(const short8*)&sAtt[(h << 7) + dd];
#pragma unroll
        for (int j = 0; j < 8; ++j) {
          float z = b2f((ushort_t)xl8[j]) + b2f((ushort_t)xr8[j])
                  + c0 * b2f((ushort_t)e08[j]) + c1 * b2f((ushort_t)e18[j]);
          dot = fmaf(leaky(z, 0.2f), b2f((ushort_t)at8[j]), dot);
        }
      }
      dot += __shfl_xor(dot, 1);
      dot += __shfl_xor(dot, 2);
      dot += __shfl_xor(dot, 4);
      if (l8 == 0) sLogitS[n] = dot;
    }
    __syncthreads();
    // E6: softmax (redundant per 8-lane node group) + vectorized aggregation
    {
      const int n = t >> 3, l8 = t & 7, db = l8 << 4;
      const u64 mb = sInc[n];
      float mx = sLogitS[n];
      u64 m2 = mb;
      while (m2) { const int e = __builtin_ctzll(m2); m2 &= m2 - 1; mx = fmaxf(mx, sLogit[e]); }
      const float es = __expf(sLogitS[n] - mx);
      float den = es;
      float S[16] = {};
      m2 = mb;
      while (m2) {
        const int e = __builtin_ctzll(m2); m2 &= m2 - 1;
        const float w = __expf(sLogit[e] - mx);
        den += w;
        const int sn = sSrc[e];
        const short8 a0 = *(const short8*)&sXl[boff(sn, db)];
        const short8 a1 = *(const short8*)&sXl[boff(sn, db + 8)];
#pragma unroll
        for (int j = 0; j < 8; ++j) {
          S[j] = fmaf(w, b2f((ushort_t)a0[j]), S[j]);
          S[8 + j] = fmaf(w, b2f((ushort_t)a1[j]), S[8 + j]);
        }
      }
      const short8 s0 = *(const short8*)&sXl[boff(n, db)];
      const short8 s1 = *(const short8*)&sXl[boff(n, db + 8)];
      const float rd = 0.25f / den;
#pragma unroll
      for (int j = 0; j < 8; ++j) {
        accH[j] = fmaf(rd, S[j] + es * b2f((ushort_t)s0[j]), accH[j]);
        accH[8 + j] = fmaf(rd, S[8 + j] + es * b2f((ushort_t)s1[j]), accH[8 + j]);
      }
    }
    __syncthreads();
  }

  // ---- gout = head-mean + gat_b -> bf16 A-matrix in sX (2 vector writes) ----
  {
    const int n = t >> 3, l8 = t & 7, db = l8 << 4;
    const float4 g0 = *(const float4*)&gatb[db];
    const float4 g1 = *(const float4*)&gatb[db + 4];
    const float4 g2 = *(const float4*)&gatb[db + 8];
    const float4 g3 = *(const float4*)&gatb[db + 12];
    const float gv[16] = {g0.x, g0.y, g0.z, g0.w, g1.x, g1.y, g1.z, g1.w,
                          g2.x, g2.y, g2.z, g2.w, g3.x, g3.y, g3.z, g3.w};
    short8 o0, o1;
#pragma unroll
    for (int j = 0; j < 8; ++j) {
      o0[j] = (short)f2b(accH[j] + gv[j]);
      o1[j] = (short)f2b(accH[8 + j] + gv[8 + j]);
    }
    *(short8*)&sX[boff(n, db)] = o0;
    *(short8*)&sX[boff(n, db + 8)] = o1;
  }
  __syncthreads();

  // ---- FFN via MFMA ----
  {
    short8 aG[2][4];
#pragma unroll
    for (int c = 0; c < 2; ++c)
#pragma unroll
      for (int q = 0; q < 4; ++q)
        aG[c][q] = *(const short8*)&sX[boff(c * 16 + (lane & 15), q * 32 + ((lane >> 4) << 3))];
    gemm_e(aG, (const ushort_t*)(ws + W1P_OFF), b1, 0.01f, sXl, lane, wave);
    __syncthreads();
#pragma unroll
    for (int c = 0; c < 2; ++c)
#pragma unroll
      for (int q = 0; q < 4; ++q)
        aG[c][q] = *(const short8*)&sXl[boff(c * 16 + (lane & 15), q * 32 + ((lane >> 4) << 3))];
    gemm_e(aG, (const ushort_t*)(ws + W2P_OFF), b2, 1.0f, sXr, lane, wave);
  }
  __syncthreads();

  // ---- masked mean pool ----
  if (t < D_) {
    float acc = 0.f;
    for (int n = 0; n < N_; ++n) acc = fmaf(b2f(sXr[boff(n, t)]), sNm[n], acc);
    sPool[t] = acc * (1.f / fmaxf(sNmSum, 1.f)) * sValid;
  }
  __syncthreads();
  // ---- LN2 + store ----
  if (t < 64) {
    const float v0 = sPool[t], v1 = sPool[t + 64];
    float s = v0 + v1, ss = v0 * v0 + v1 * v1;
#pragma unroll
    for (int m = 1; m < 64; m <<= 1) { s += __shfl_xor(s, m); ss += __shfl_xor(ss, m); }
    const float mu = s * (1.f / 128.f);
    const float inv = rsqrtf(ss * (1.f / 128.f) - mu * mu + 1e-5f);
    float* op = out + (size_t)g * D_;
    __builtin_nontemporal_store((v0 - mu) * inv * ln2g[t] + ln2b[t], op + t);
    __builtin_nontemporal_store((v1 - mu) * inv * ln2g[t + 64] + ln2b[t + 64], op + t + 64);
  }
}

extern "C" void kernel_launch(void* const* d_in, const int* in_sizes, int n_in,
                              void* d_out, int out_size, void* d_ws, size_t ws_size,
                              hipStream_t stream) {
  (void)in_sizes; (void)n_in; (void)out_size; (void)ws_size;
  const float* qe   = (const float*)d_in[0];
  const int*   qm   = (const int*)d_in[1];
  const int*   ei   = (const int*)d_in[2];
  const int*   ew   = (const int*)d_in[3];
  const int*   em   = (const int*)d_in[4];
  const float* ln1g = (const float*)d_in[5];
  const float* ln1b = (const float*)d_in[6];
  const float* embT = (const float*)d_in[7];
  const float* Wl   = (const float*)d_in[8];
  const float* bl   = (const float*)d_in[9];
  const float* Wr   = (const float*)d_in[10];
  const float* br   = (const float*)d_in[11];
  const float* We   = (const float*)d_in[12];
  const float* att  = (const float*)d_in[13];
  const float* gatb = (const float*)d_in[14];
  const float* W1   = (const float*)d_in[15];
  const float* b1   = (const float*)d_in[16];
  const float* W2   = (const float*)d_in[17];
  const float* b2   = (const float*)d_in[18];
  const float* ln2g = (const float*)d_in[19];
  const float* ln2b = (const float*)d_in[20];
  float* out = (float*)d_out;
  unsigned char* ws = (unsigned char*)d_ws;

  pack_weights<<<dim3(324), dim3(256), 0, stream>>>(Wl, Wr, W1, W2, embT, We, ws);
  gat_main<<<dim3(G_), dim3(256), 0, stream>>>(ws, qe, ln1g, ln1b, qm, ei, ew, em,
                                               bl, br, att, gatb, b1, b2, ln2g, ln2b, out);
}